// Round 3
// baseline (996.105 us; speedup 1.0000x reference)
//
#include <hip/hip_runtime.h>
#include <math.h>

// Instant-NGP multi-res hash grid encoder, MI355X (gfx950).
// One thread per (point, level): level = lane & 15, so
//  - lanes 0..15 share one point's x (same-cache-line broadcast reads)
//  - per-wave output stores are 512 contiguous bytes (out[t] linear in t)
// 8 float2 gathers per thread issued back-to-back for latency overlap;
// nontemporal output stores keep the 128 MB write stream from evicting
// hot hash-table lines out of L2.

#define LEVELS 16
#define LOG2_T 19
#define TMASK ((1u << LOG2_T) - 1u)

// __builtin_nontemporal_store needs a native vector type, not
// HIP_vector_type<float,2> (round-2 compile error).
typedef float f32x2 __attribute__((ext_vector_type(2)));

struct ResArgs { float r[LEVELS]; };

__global__ __launch_bounds__(256) void ngp_encode_kernel(
    const float* __restrict__ x,
    const float* __restrict__ table,
    f32x2* __restrict__ out,
    ResArgs res,
    unsigned n_points)
{
    const unsigned t = blockIdx.x * 256u + threadIdx.x;
    const unsigned level = t & (LEVELS - 1u);
    const unsigned p = t >> 4;
    if (p >= n_points) return;

    // 16 consecutive lanes read the same point -> 1-2 lines per wave.
    const float x0 = x[3u * p + 0u];
    const float x1 = x[3u * p + 1u];
    const float x2 = x[3u * p + 2u];

    // Same fp32 op chain as the reference: s = x * float(res); floor; frac.
    const float rf = res.r[level];
    const float sx = x0 * rf, sy = x1 * rf, sz = x2 * rf;
    const float px = floorf(sx), py = floorf(sy), pz = floorf(sz);
    const float fx = sx - px, fy = sy - py, fz = sz - pz;
    const unsigned ix = (unsigned)px, iy = (unsigned)py, iz = (unsigned)pz;

    // Hash: (cx*1) ^ (cy*2654435761) ^ (cz*805459861), uint32 wrap, & (T-1).
    const unsigned hx0 = ix;
    const unsigned hx1 = ix + 1u;
    const unsigned hy0 = iy * 2654435761u;
    const unsigned hy1 = hy0 + 2654435761u;
    const unsigned hz0 = iz * 805459861u;
    const unsigned hz1 = hz0 + 805459861u;

    const f32x2* __restrict__ tbl =
        (const f32x2*)table + ((size_t)level << LOG2_T);

    const unsigned i000 = (hx0 ^ hy0 ^ hz0) & TMASK;
    const unsigned i100 = (hx1 ^ hy0 ^ hz0) & TMASK;
    const unsigned i010 = (hx0 ^ hy1 ^ hz0) & TMASK;
    const unsigned i110 = (hx1 ^ hy1 ^ hz0) & TMASK;
    const unsigned i001 = (hx0 ^ hy0 ^ hz1) & TMASK;
    const unsigned i101 = (hx1 ^ hy0 ^ hz1) & TMASK;
    const unsigned i011 = (hx0 ^ hy1 ^ hz1) & TMASK;
    const unsigned i111 = (hx1 ^ hy1 ^ hz1) & TMASK;

    // 8 independent gathers: issue all before any use (latency overlap).
    const f32x2 c000 = tbl[i000];
    const f32x2 c100 = tbl[i100];
    const f32x2 c010 = tbl[i010];
    const f32x2 c110 = tbl[i110];
    const f32x2 c001 = tbl[i001];
    const f32x2 c101 = tbl[i101];
    const f32x2 c011 = tbl[i011];
    const f32x2 c111 = tbl[i111];

    // Trilinear weights; corner bit d of corner i -> (i>>d)&1 (x is bit 0).
    const float wx1 = fx, wx0 = 1.0f - fx;
    const float wy1 = fy, wy0 = 1.0f - fy;
    const float wz1 = fz, wz0 = 1.0f - fz;
    const float w00 = wy0 * wz0;
    const float w10 = wy1 * wz0;
    const float w01 = wy0 * wz1;
    const float w11 = wy1 * wz1;

    float w, a0, a1;
    w = wx0 * w00; a0 = w * c000.x;          a1 = w * c000.y;
    w = wx1 * w00; a0 = fmaf(w, c100.x, a0); a1 = fmaf(w, c100.y, a1);
    w = wx0 * w10; a0 = fmaf(w, c010.x, a0); a1 = fmaf(w, c010.y, a1);
    w = wx1 * w10; a0 = fmaf(w, c110.x, a0); a1 = fmaf(w, c110.y, a1);
    w = wx0 * w01; a0 = fmaf(w, c001.x, a0); a1 = fmaf(w, c001.y, a1);
    w = wx1 * w01; a0 = fmaf(w, c101.x, a0); a1 = fmaf(w, c101.y, a1);
    w = wx0 * w11; a0 = fmaf(w, c011.x, a0); a1 = fmaf(w, c011.y, a1);
    w = wx1 * w11; a0 = fmaf(w, c111.x, a0); a1 = fmaf(w, c111.y, a1);

    f32x2 o; o.x = a0; o.y = a1;
    // out index == t exactly (p*16 + level): perfectly coalesced, write-once
    // 128 MB stream -> nontemporal.
    __builtin_nontemporal_store(o, &out[t]);
}

extern "C" void kernel_launch(void* const* d_in, const int* in_sizes, int n_in,
                              void* d_out, int out_size, void* d_ws, size_t ws_size,
                              hipStream_t stream) {
    const float* x     = (const float*)d_in[0];
    const float* table = (const float*)d_in[1];
    const unsigned n_points = (unsigned)(in_sizes[0] / 3);

    // Replicate numpy's RES computation chain (same host, same libm as the
    // reference's module-level numpy: DOUBLE_power -> libm pow per element):
    // scale = exp((log(512)-log(16))/15); res[l] = floor(16 * scale**l).
    // Boundary levels l in {3,6,9,12,15} sit on exact powers of two -- if
    // correctness ever fails, these are the suspects (off-by-one in floor).
    ResArgs res;
    const double scale = exp((log(512.0) - log(16.0)) / 15.0);
    for (int l = 0; l < LEVELS; ++l) {
        res.r[l] = (float)floor(16.0 * pow(scale, (double)l));
    }

    const unsigned total = n_points * LEVELS;
    const unsigned nblk = (total + 255u) / 256u;
    ngp_encode_kernel<<<dim3(nblk), dim3(256), 0, stream>>>(
        x, table, (f32x2*)d_out, res, n_points);
}